// Round 16
// baseline (54.497 us; speedup 1.0000x reference)
//
#include <hip/hip_runtime.h>

// DCNv3 forward, fp32 in/out. Layouts (from the reference's view-reshapes):
//   x   : (B=4, H=128, W=128, C=128) flat — idx = ((b*128+h)*128+w)*128+c
//   out : same
//   W_off (128,72), b_off(72), W_mask(128,36), b_mask(36)
// Tier-1 ws layout:
//   [0)        x16 : bf16 copy of x, GROUP-PLANAR (16 MB):
//              x16[((cg*4+b)*16384 + y*128 + xq)*32 + ch], ch in [0,32)
//   [16 MB)    ws16: fp16 AoS records (16 MB): per (pixel,group) 64B record
//              at ws16[pix*128 + g*32]: [0..17]=offsets, [18..26]=logits,
//              [27..31]=pad.
//   [32 MB)    wpk : MFMA B-fragment weights (32 KB, uint = bf16 k-pair)
//   [+32 KB)   wb  : bias fp32 [4][32]
// Lessons: R7 no reg-array batching (spill); R10 no MFMA+gather single-block
// fusion; R13/R14 no extra passes over x/x16; R15 wlds staging ~ worthless.
// R16: the lin grid (1024 = 4 blocks/CU) was the binding constraint, and the
// x16 pack is FREE inside the MFMA linear — afr[kt] IS plane-kt's bf16 data,
// and lane (lhi,lrow) stores it densely (1KB/wave-store). lin4 = 4096
// one-wave blocks: A-frags from x fp32 (R14 path) -> afr -> {x16 store,
// MFMA vs L2-hot wpk} -> 4.4KB LDS transpose -> dense ws16 records.

#define NPIX 65536  // B*H*W

typedef unsigned int uint;
typedef unsigned short ushort;
typedef __attribute__((ext_vector_type(8))) short short8v;   // 8 bf16
typedef __attribute__((ext_vector_type(4))) float f32x4;

__device__ __forceinline__ ushort f2bf(float f) {
  uint u = __float_as_uint(f);
  u += 0x7FFFu + ((u >> 16) & 1u);  // RNE
  return (ushort)(u >> 16);
}
__device__ __forceinline__ uint pkbf(float lo, float hi) {
  return (uint)f2bf(lo) | ((uint)f2bf(hi) << 16);
}
__device__ __forceinline__ float bflo(uint d) { return __uint_as_float(d << 16); }
__device__ __forceinline__ float bfhi(uint d) { return __uint_as_float(d & 0xFFFF0000u); }
__device__ __forceinline__ ushort f2h(float f) {
  union { _Float16 h; ushort u; } cv;
  cv.h = (_Float16)f;
  return cv.u;
}
__device__ __forceinline__ float h2f_lo(uint u) {
  union { ushort s; _Float16 h; } cv;
  cv.s = (ushort)(u & 0xFFFFu);
  return (float)cv.h;
}
__device__ __forceinline__ float h2f_hi(uint u) {
  union { ushort s; _Float16 h; } cv;
  cv.s = (ushort)(u >> 16);
  return (float)cv.h;
}

union U8 { uint u[4]; short8v v; };

__device__ __forceinline__ float wcol(const float* __restrict__ Woff,
                                      const float* __restrict__ Wmask,
                                      int g, int k, int n) {
  if (n < 18) return Woff[k * 72 + g * 18 + n];
  if (n < 27) return Wmask[k * 36 + g * 9 + (n - 18)];
  return 0.f;
}

// ---------------- Kernel W: weight fragment pack (trivial) ----------------
__global__ __launch_bounds__(256) void dcn_wpack(
    const float* __restrict__ Woff, const float* __restrict__ boff,
    const float* __restrict__ Wmask, const float* __restrict__ bmask,
    uint* __restrict__ wpk, float* __restrict__ wb) {
  const int idx = (blockIdx.x << 8) + threadIdx.x;  // grid 32 -> 8192
  {
    const int f = idx >> 8;
    const int widx = idx & 255;
    const int lane = widx >> 2, epair = widx & 3;
    const int kt = f & 3, nt = (f >> 2) & 1, g = f >> 3;
    const int k0 = kt * 32 + (lane >> 4) * 8 + epair * 2;
    const int n = nt * 16 + (lane & 15);
    wpk[idx] = pkbf(wcol(Woff, Wmask, g, k0, n), wcol(Woff, Wmask, g, k0 + 1, n));
  }
  if (blockIdx.x == 0 && threadIdx.x < 128) {
    const int g = threadIdx.x >> 5, n = threadIdx.x & 31;
    float bv;
    if (n < 18) bv = boff[g * 18 + n];
    else if (n < 27) bv = bmask[g * 9 + (n - 18)];
    else bv = 0.f;
    wb[threadIdx.x] = bv;
  }
}

// ---------------- Kernel A: one-wave MFMA linear + FUSED x16 pack ----------
// grid 4096 x 64 (1 wave, 16 px) -> 16 blocks/CU. Per lane (lrow=lane&15 px,
// lhi=lane>>4 k-quarter): load x fp32 (4 kt x 32B dense chunks), convert to
// afr; afr[kt] IS x16 plane-kt data -> 4 dense uint4 stores; MFMA vs L2-hot
// wpk; 272B-stride LDS transpose; dense 4KB ws16 record copy.
__global__ __launch_bounds__(64) void dcn_lin4(
    const float* __restrict__ x, const uint* __restrict__ wpk,
    const float* __restrict__ wb, ushort* __restrict__ ws16,
    ushort* __restrict__ x16) {
  __shared__ __align__(16) ushort rec[16 * 136];  // 4352 B
  const int pbase = blockIdx.x << 4;  // 16 px per block
  const int lane = threadIdx.x;
  const int lrow = lane & 15;  // A row (px) / B col (n)
  const int lhi = lane >> 4;   // k sub-block
  const int pixrow = pbase + lrow;
  const int b = pbase >> 14;
  const int yx = pixrow & 16383;

  // ---- A-frags from x fp32 (dense 128B chunks per kt) + bf16 convert ----
  U8 afr[4];
#pragma unroll
  for (int kt = 0; kt < 4; ++kt) {
    const float* ax = x + (size_t)pixrow * 128 + (kt << 5) + (lhi << 3);
    const float4 xa = *(const float4*)ax;
    const float4 xb4 = *(const float4*)(ax + 4);
    afr[kt].u[0] = pkbf(xa.x, xa.y);   afr[kt].u[1] = pkbf(xa.z, xa.w);
    afr[kt].u[2] = pkbf(xb4.x, xb4.y); afr[kt].u[3] = pkbf(xb4.z, xb4.w);
  }

  // ---- fused x16 pack: afr[kt] = plane kt, lane-dense 1KB wave-stores ----
#pragma unroll
  for (int kt = 0; kt < 4; ++kt) {
    uint4 s;
    s.x = afr[kt].u[0]; s.y = afr[kt].u[1];
    s.z = afr[kt].u[2]; s.w = afr[kt].u[3];
    *(uint4*)(x16 + ((((size_t)((kt << 2) | b) << 14) | yx) << 5) + (lhi << 3)) = s;
  }

  // ---- MFMA vs wpk (L2-hot) ----
  f32x4 acc[4][2];
#pragma unroll
  for (int g = 0; g < 4; ++g)
#pragma unroll
    for (int nt = 0; nt < 2; ++nt) {
      const float bv = wb[(g << 5) + (nt << 4) + lrow];
      acc[g][nt] = (f32x4){bv, bv, bv, bv};
    }

#pragma unroll
  for (int kt = 0; kt < 4; ++kt)
#pragma unroll
    for (int g = 0; g < 4; ++g)
#pragma unroll
      for (int nt = 0; nt < 2; ++nt) {
        U8 bf;
        const uint4 bv =
            *(const uint4*)(wpk + ((g << 3) + (nt << 2) + kt) * 256 + (lane << 2));
        bf.u[0] = bv.x; bf.u[1] = bv.y; bf.u[2] = bv.z; bf.u[3] = bv.w;
        acc[g][nt] =
            __builtin_amdgcn_mfma_f32_16x16x32_bf16(afr[kt].v, bf.v, acc[g][nt], 0, 0, 0);
      }

  // ---- transpose to records (C/D m89-verified: col=lane&15, row=(lane>>4)*4+j)
  {
    const int px0 = lhi << 2;
#pragma unroll
    for (int g = 0; g < 4; ++g)
#pragma unroll
      for (int nt = 0; nt < 2; ++nt)
#pragma unroll
        for (int j = 0; j < 4; ++j)
          rec[(px0 + j) * 136 + (g << 5) + (nt << 4) + lrow] = f2h(acc[g][nt][j]);
  }
  __syncthreads();  // single wave: orders LDS writes before reads

  // ---- dense copy LDS -> ws16 (4 KB) ----
  {
    ushort* dst = ws16 + (size_t)pbase * 128;
#pragma unroll
    for (int i = 0; i < 4; ++i) {
      const int chunk = (i << 6) + lane;  // 256 chunks x 8 ushorts
      const int px = chunk >> 4;
      const int c8 = (chunk & 15) << 3;
      const uint4 v = *(const uint4*)(rec + px * 136 + c8);
      *(uint4*)(dst + (size_t)chunk * 8) = v;
    }
  }
}

// ---------------- Kernel B: bilinear gather (R9-proven, verbatim) ----------
__global__ __launch_bounds__(256) void dcn_samp(
    const ushort* __restrict__ x16, const ushort* __restrict__ ws16,
    float* __restrict__ out) {
  const int g = blockIdx.x & 3;
  const int pg = threadIdx.x >> 2;   // 0..63: pixel within block
  const int sub = threadIdx.x & 3;   // 16B chunk within the group slice
  const int q = ((blockIdx.x >> 2) << 6) | pg;
  const int b = q >> 14;
  const int h = (q >> 7) & 127;
  const int w = q & 127;
  const ushort* xg = x16 + (((size_t)((g << 2) | b)) << 19) + (sub << 3);

  const ushort* wsrec = ws16 + (size_t)q * 128 + (g << 5);
  const uint4 r0 = *(const uint4*)(wsrec);
  const uint4 r1 = *(const uint4*)(wsrec + 8);
  const uint4 r2 = *(const uint4*)(wsrec + 16);
  const uint2 r3 = *(const uint2*)(wsrec + 24);
  const uint rr0 = r0.x, rr1 = r0.y, rr2 = r0.z, rr3 = r0.w;
  const uint rr4 = r1.x, rr5 = r1.y, rr6 = r1.z, rr7 = r1.w;
  const uint rr8 = r2.x, rr9 = r2.y, rr10 = r2.z, rr11 = r2.w;
  const uint rr12 = r3.x, rr13 = r3.y;

  float offx9[9], offy9[9], mk9[9];
  {
    const uint rra[14] = {rr0, rr1, rr2,  rr3,  rr4,  rr5,  rr6,
                          rr7, rr8, rr9, rr10, rr11, rr12, rr13};
#pragma unroll
    for (int p = 0; p < 9; ++p) {
      offx9[p] = h2f_lo(rra[p]);
      offy9[p] = h2f_hi(rra[p]);
      const int li = 18 + p;
      mk9[p] = (li & 1) ? h2f_hi(rra[li >> 1]) : h2f_lo(rra[li >> 1]);
    }
    float mx = mk9[0];
#pragma unroll
    for (int p = 1; p < 9; ++p) mx = fmaxf(mx, mk9[p]);
    float s = 0.f;
#pragma unroll
    for (int p = 0; p < 9; ++p) {
      mk9[p] = __expf(mk9[p] - mx);
      s += mk9[p];
    }
    const float sinv = 1.0f / s;
#pragma unroll
    for (int p = 0; p < 9; ++p) mk9[p] *= sinv;
  }

  float a0 = 0.f, a1 = 0.f, a2 = 0.f, a3 = 0.f;
  float a4 = 0.f, a5 = 0.f, a6 = 0.f, a7 = 0.f;

#pragma unroll
  for (int p = 0; p < 9; ++p) {
    const float mk = mk9[p];
    const float px = (float)(w + p / 3) + offx9[p];
    const float py = (float)(h + p % 3) + offy9[p];
    const float fx = floorf(px), fy = floorf(py);
    const float tx = px - fx, ty = py - fy;
    const int x0 = (int)fx - 1, y0 = (int)fy - 1;
    const int x1 = x0 + 1, y1 = y0 + 1;
    const float ax0 = ((unsigned)x0 < 128u) ? (1.f - tx) : 0.f;
    const float ax1 = ((unsigned)x1 < 128u) ? tx : 0.f;
    const float ay0 = ((unsigned)y0 < 128u) ? (mk * (1.f - ty)) : 0.f;
    const float ay1 = ((unsigned)y1 < 128u) ? (mk * ty) : 0.f;
    const float w00 = ax0 * ay0, w10 = ax1 * ay0;
    const float w01 = ax0 * ay1, w11 = ax1 * ay1;
    const int cx0 = min(max(x0, 0), 127), cy0 = min(max(y0, 0), 127);
    const int cx1 = min(max(x1, 0), 127), cy1 = min(max(y1, 0), 127);
    const int o00 = ((cy0 << 7) | cx0) << 5;
    const int o10 = ((cy0 << 7) | cx1) << 5;
    const int o01 = ((cy1 << 7) | cx0) << 5;
    const int o11 = ((cy1 << 7) | cx1) << 5;
    const uint4 d00 = *(const uint4*)(xg + o00);
    const uint4 d10 = *(const uint4*)(xg + o10);
    const uint4 d01 = *(const uint4*)(xg + o01);
    const uint4 d11 = *(const uint4*)(xg + o11);
    a0 = fmaf(w00, bflo(d00.x), fmaf(w10, bflo(d10.x),
         fmaf(w01, bflo(d01.x), fmaf(w11, bflo(d11.x), a0))));
    a1 = fmaf(w00, bfhi(d00.x), fmaf(w10, bfhi(d10.x),
         fmaf(w01, bfhi(d01.x), fmaf(w11, bfhi(d11.x), a1))));
    a2 = fmaf(w00, bflo(d00.y), fmaf(w10, bflo(d10.y),
         fmaf(w01, bflo(d01.y), fmaf(w11, bflo(d11.y), a2))));
    a3 = fmaf(w00, bfhi(d00.y), fmaf(w10, bfhi(d10.y),
         fmaf(w01, bfhi(d01.y), fmaf(w11, bfhi(d11.y), a3))));
    a4 = fmaf(w00, bflo(d00.z), fmaf(w10, bflo(d10.z),
         fmaf(w01, bflo(d01.z), fmaf(w11, bflo(d11.z), a4))));
    a5 = fmaf(w00, bfhi(d00.z), fmaf(w10, bfhi(d10.z),
         fmaf(w01, bfhi(d01.z), fmaf(w11, bfhi(d11.z), a5))));
    a6 = fmaf(w00, bflo(d00.w), fmaf(w10, bflo(d10.w),
         fmaf(w01, bflo(d01.w), fmaf(w11, bflo(d11.w), a6))));
    a7 = fmaf(w00, bfhi(d00.w), fmaf(w10, bfhi(d10.w),
         fmaf(w01, bfhi(d01.w), fmaf(w11, bfhi(d11.w), a7))));
  }

  float* op = out + (size_t)q * 128 + (g << 5) + (sub << 3);
  float4 oa, ob;
  oa.x = a0; oa.y = a1; oa.z = a2; oa.w = a3;
  ob.x = a4; ob.y = a5; ob.z = a6; ob.w = a7;
  *(float4*)op = oa;
  *(float4*)(op + 4) = ob;
}

// ---------------- Tier-2 fallback: legacy VALU lin (with softmax) ----------
__global__ __launch_bounds__(256) void dcn_lin(
    const float* __restrict__ x, const float* __restrict__ Woff,
    const float* __restrict__ boff, const float* __restrict__ Wmask,
    const float* __restrict__ bmask, float* __restrict__ ws) {
  const int jg = blockIdx.x >> 8;
  const int pix = ((blockIdx.x & 255) << 8) | threadIdx.x;
  const float* W;
  const float* bias;
  int ldw, obase;
  if (jg == 0) {
    W = Woff; bias = boff; ldw = 72; obase = 0;
  } else if (jg == 1) {
    W = Woff + 36; bias = boff + 36; ldw = 72; obase = 36;
  } else {
    W = Wmask; bias = bmask; ldw = 36; obase = 72;
  }
  float acc[36];
#pragma unroll
  for (int j = 0; j < 36; ++j) acc[j] = bias[j];
  const float* xp = x + (size_t)pix * 128;
  for (int c0 = 0; c0 < 128; c0 += 8) {
    float xr[8];
    *(float4*)(xr) = *(const float4*)(xp + c0);
    *(float4*)(xr + 4) = *(const float4*)(xp + c0 + 4);
#pragma unroll
    for (int cc = 0; cc < 8; ++cc) {
      const float xc = xr[cc];
      const float* wr = W + (size_t)(c0 + cc) * ldw;
#pragma unroll
      for (int j = 0; j < 36; ++j) acc[j] = fmaf(xc, wr[j], acc[j]);
    }
  }
  if (jg == 2) {
#pragma unroll
    for (int g = 0; g < 4; ++g) {
      float mx = acc[g * 9];
#pragma unroll
      for (int p = 1; p < 9; ++p) mx = fmaxf(mx, acc[g * 9 + p]);
      float s = 0.f;
#pragma unroll
      for (int p = 0; p < 9; ++p) {
        acc[g * 9 + p] = __expf(acc[g * 9 + p] - mx);
        s += acc[g * 9 + p];
      }
      const float sinv = 1.0f / s;
#pragma unroll
      for (int p = 0; p < 9; ++p) acc[g * 9 + p] *= sinv;
    }
  }
#pragma unroll
  for (int j = 0; j < 36; ++j) ws[(size_t)(obase + j) * NPIX + pix] = acc[j];
}

// ---------------- Tier-2 fallback: fp32 gather (R2-proven) ----------------
__global__ __launch_bounds__(256) void dcn_samp_f32(
    const float* __restrict__ x, const float* __restrict__ ws,
    float* __restrict__ out) {
  const int q = (blockIdx.x << 4) | (threadIdx.x >> 4);
  const int sub = threadIdx.x & 15;
  const int c = sub << 3;
  const int g = sub >> 2;
  const int b = q >> 14;
  const int h = (q >> 7) & 127;
  const int w = q & 127;
  const float* xb = x + ((size_t)b << 21) + c;
  const float* wsq = ws + q;
  float a0 = 0.f, a1 = 0.f, a2 = 0.f, a3 = 0.f;
  float a4 = 0.f, a5 = 0.f, a6 = 0.f, a7 = 0.f;
#pragma unroll
  for (int p = 0; p < 9; ++p) {
    const float offx = wsq[(size_t)(g * 18 + p * 2) * NPIX];
    const float offy = wsq[(size_t)(g * 18 + p * 2 + 1) * NPIX];
    const float mk = wsq[(size_t)(72 + g * 9 + p) * NPIX];
    const float px = (float)(w + p / 3) + offx;
    const float py = (float)(h + p % 3) + offy;
    const float fx = floorf(px), fy = floorf(py);
    const float tx = px - fx, ty = py - fy;
    const int x0 = (int)fx - 1, y0 = (int)fy - 1;
    const int x1 = x0 + 1, y1 = y0 + 1;
    const float ax0 = ((unsigned)x0 < 128u) ? (1.f - tx) : 0.f;
    const float ax1 = ((unsigned)x1 < 128u) ? tx : 0.f;
    const float ay0 = ((unsigned)y0 < 128u) ? (mk * (1.f - ty)) : 0.f;
    const float ay1 = ((unsigned)y1 < 128u) ? (mk * ty) : 0.f;
    const float w00 = ax0 * ay0, w10 = ax1 * ay0;
    const float w01 = ax0 * ay1, w11 = ax1 * ay1;
    const int cx0 = min(max(x0, 0), 127), cy0 = min(max(y0, 0), 127);
    const int cx1 = min(max(x1, 0), 127), cy1 = min(max(y1, 0), 127);
    const int o00 = (cy0 << 14) | (cx0 << 7), o10 = (cy0 << 14) | (cx1 << 7);
    const int o01 = (cy1 << 14) | (cx0 << 7), o11 = (cy1 << 14) | (cx1 << 7);
    const float4 v00a = *(const float4*)(xb + o00);
    const float4 v00b = *(const float4*)(xb + o00 + 4);
    const float4 v10a = *(const float4*)(xb + o10);
    const float4 v10b = *(const float4*)(xb + o10 + 4);
    const float4 v01a = *(const float4*)(xb + o01);
    const float4 v01b = *(const float4*)(xb + o01 + 4);
    const float4 v11a = *(const float4*)(xb + o11);
    const float4 v11b = *(const float4*)(xb + o11 + 4);
    a0 = fmaf(w00, v00a.x, fmaf(w10, v10a.x, fmaf(w01, v01a.x, fmaf(w11, v11a.x, a0))));
    a1 = fmaf(w00, v00a.y, fmaf(w10, v10a.y, fmaf(w01, v01a.y, fmaf(w11, v11a.y, a1))));
    a2 = fmaf(w00, v00a.z, fmaf(w10, v10a.z, fmaf(w01, v01a.z, fmaf(w11, v11a.z, a2))));
    a3 = fmaf(w00, v00a.w, fmaf(w10, v10a.w, fmaf(w01, v01a.w, fmaf(w11, v11a.w, a3))));
    a4 = fmaf(w00, v00b.x, fmaf(w10, v10b.x, fmaf(w01, v01b.x, fmaf(w11, v11b.x, a4))));
    a5 = fmaf(w00, v00b.y, fmaf(w10, v10b.y, fmaf(w01, v01b.y, fmaf(w11, v11b.y, a5))));
    a6 = fmaf(w00, v00b.z, fmaf(w10, v10b.z, fmaf(w01, v01b.z, fmaf(w11, v11b.z, a6))));
    a7 = fmaf(w00, v00b.w, fmaf(w10, v10b.w, fmaf(w01, v01b.w, fmaf(w11, v11b.w, a7))));
  }
  float4 oa, ob;
  oa.x = a0; oa.y = a1; oa.z = a2; oa.w = a3;
  ob.x = a4; ob.y = a5; ob.z = a6; ob.w = a7;
  float* op = out + (size_t)q * 128 + c;
  *(float4*)op = oa;
  *(float4*)(op + 4) = ob;
}

// ---------------- Tier-3 fallback: fully fused ----------------
__global__ __launch_bounds__(128) void dcn_fused(
    const float* __restrict__ x, const float* __restrict__ Woff,
    const float* __restrict__ boff, const float* __restrict__ Wmask,
    const float* __restrict__ bmask, float* __restrict__ out) {
  __shared__ float xs[128];
  __shared__ float res[108];
  __shared__ float msk[36];
  const int q = blockIdx.x;
  const int t = threadIdx.x;
  const int b = q >> 14, h = (q >> 7) & 127, w = q & 127;
  xs[t] = x[(size_t)q * 128 + t];
  __syncthreads();
  if (t < 108) {
    float a;
    const float* W;
    int ld;
    if (t < 72) {
      a = boff[t]; W = Woff + t; ld = 72;
    } else {
      a = bmask[t - 72]; W = Wmask + (t - 72); ld = 36;
    }
    for (int cc = 0; cc < 128; ++cc) a = fmaf(xs[cc], W[(size_t)cc * ld], a);
    res[t] = a;
  }
  __syncthreads();
  if (t < 4) {
    float mx = -1e30f;
    for (int p = 0; p < 9; ++p) mx = fmaxf(mx, res[72 + t * 9 + p]);
    float s = 0.f;
    float e[9];
    for (int p = 0; p < 9; ++p) {
      e[p] = __expf(res[72 + t * 9 + p] - mx);
      s += e[p];
    }
    for (int p = 0; p < 9; ++p) msk[t * 9 + p] = e[p] / s;
  }
  __syncthreads();
  const int g = t >> 5;
  const float* xb = x + ((size_t)b << 21) + t;
  float acc = 0.f;
#pragma unroll
  for (int p = 0; p < 9; ++p) {
    const float offx = res[g * 18 + p * 2];
    const float offy = res[g * 18 + p * 2 + 1];
    const float px = (float)(w + p / 3) + offx;
    const float py = (float)(h + p % 3) + offy;
    const float fx = floorf(px), fy = floorf(py);
    const float tx = px - fx, ty = py - fy;
    const int x0 = (int)fx - 1, y0 = (int)fy - 1;
    float sv = 0.f;
#define CORNER1(XI, YI, WT)                                       \
  if ((unsigned)(XI) < 128u && (unsigned)(YI) < 128u)             \
    sv = fmaf((WT), xb[((size_t)(YI) << 14) + ((size_t)(XI) << 7)], sv);
    CORNER1(x0, y0, (1.f - tx) * (1.f - ty))
    CORNER1(x0 + 1, y0, tx * (1.f - ty))
    CORNER1(x0, y0 + 1, (1.f - tx) * ty)
    CORNER1(x0 + 1, y0 + 1, tx * ty)
#undef CORNER1
    acc = fmaf(msk[g * 9 + p], sv, acc);
  }
  out[(size_t)q * 128 + t] = acc;
}

extern "C" void kernel_launch(void* const* d_in, const int* in_sizes, int n_in,
                              void* d_out, int out_size, void* d_ws,
                              size_t ws_size, hipStream_t stream) {
  const float* x = (const float*)d_in[0];
  const float* Woff = (const float*)d_in[1];
  const float* boff = (const float*)d_in[2];
  const float* Wmask = (const float*)d_in[3];
  const float* bmask = (const float*)d_in[4];
  float* out = (float*)d_out;
  const size_t x16_bytes = (size_t)NPIX * 128 * sizeof(ushort);   // 16 MB
  const size_t ws16_bytes = (size_t)NPIX * 128 * sizeof(ushort);  // 16 MB
  const size_t wpk_bytes = 8192 * sizeof(uint);                   // 32 KB
  const size_t need_full = x16_bytes + ws16_bytes + wpk_bytes + 512;
  const size_t need_ws = (size_t)NPIX * 108 * sizeof(float);
  if (ws_size >= need_full) {
    ushort* x16 = (ushort*)d_ws;
    ushort* ws16 = (ushort*)((char*)d_ws + x16_bytes);
    uint* wpk = (uint*)((char*)d_ws + x16_bytes + ws16_bytes);
    float* wb = (float*)((char*)d_ws + x16_bytes + ws16_bytes + wpk_bytes);
    dcn_wpack<<<32, 256, 0, stream>>>(Woff, boff, Wmask, bmask, wpk, wb);
    dcn_lin4<<<4096, 64, 0, stream>>>(x, wpk, wb, ws16, x16);
    dcn_samp<<<4096, 256, 0, stream>>>(x16, ws16, out);
  } else if (ws_size >= need_ws) {
    float* ws = (float*)d_ws;
    dcn_lin<<<768, 256, 0, stream>>>(x, Woff, boff, Wmask, bmask, ws);
    dcn_samp_f32<<<4096, 256, 0, stream>>>(x, ws, out);
  } else {
    dcn_fused<<<NPIX, 128, 0, stream>>>(x, Woff, boff, Wmask, bmask, out);
  }
}

// Round 17
// 51.877 us; speedup vs baseline: 1.0505x; 1.0505x over previous
//
#include <hip/hip_runtime.h>

// DCNv3 forward, fp32 in/out. Layouts (from the reference's view-reshapes):
//   x   : (B=4, H=128, W=128, C=128) flat — idx = ((b*128+h)*128+w)*128+c
//   out : same
//   W_off (128,72), b_off(72), W_mask(128,36), b_mask(36)
// Tier-1 ws layout:
//   [0)        x16 : bf16 copy of x, GROUP-PLANAR (16 MB):
//              x16[((cg*4+b)*16384 + y*128 + xq)*32 + ch], ch in [0,32)
//   [16 MB)    ws16: fp16 AoS records (16 MB): per (pixel,group) 64B record
//              at ws16[pix*128 + g*32]: [0..17]=offsets, [18..26]=logits,
//              [27..31]=pad.
//   [32 MB)    wpk : MFMA B-fragment weights (32 KB, uint = bf16 k-pair)
//   [+32 KB)   wb  : bias fp32 [4][32]
// Lessons: R7 no reg-array batching under a VGPR CAP (spill); R10 no
// MFMA+gather single-block fusion; R13/R14 no extra passes over x/x16.
// R17 (this round): R9's lin profile showed VGPR_Count=44 (acc=28+afr=16 =
// zero load headroom) -> every load serialized -> ~60 exposed round-trips/wave
// -> the invariant ~30us across ALL lin variants. Fix: __launch_bounds__(256,2)
// raises the budget to 256 VGPR so loads pipeline. Only change vs R15.

#define NPIX 65536  // B*H*W

typedef unsigned int uint;
typedef unsigned short ushort;
typedef __attribute__((ext_vector_type(8))) short short8v;   // 8 bf16
typedef __attribute__((ext_vector_type(4))) float f32x4;

__device__ __forceinline__ ushort f2bf(float f) {
  uint u = __float_as_uint(f);
  u += 0x7FFFu + ((u >> 16) & 1u);  // RNE
  return (ushort)(u >> 16);
}
__device__ __forceinline__ uint pkbf(float lo, float hi) {
  return (uint)f2bf(lo) | ((uint)f2bf(hi) << 16);
}
__device__ __forceinline__ float bflo(uint d) { return __uint_as_float(d << 16); }
__device__ __forceinline__ float bfhi(uint d) { return __uint_as_float(d & 0xFFFF0000u); }
__device__ __forceinline__ ushort f2h(float f) {
  union { _Float16 h; ushort u; } cv;
  cv.h = (_Float16)f;
  return cv.u;
}
__device__ __forceinline__ float h2f_lo(uint u) {
  union { ushort s; _Float16 h; } cv;
  cv.s = (ushort)(u & 0xFFFFu);
  return (float)cv.h;
}
__device__ __forceinline__ float h2f_hi(uint u) {
  union { ushort s; _Float16 h; } cv;
  cv.s = (ushort)(u >> 16);
  return (float)cv.h;
}

union U8 { uint u[4]; short8v v; };

__device__ __forceinline__ float wcol(const float* __restrict__ Woff,
                                      const float* __restrict__ Wmask,
                                      int g, int k, int n) {
  if (n < 18) return Woff[k * 72 + g * 18 + n];
  if (n < 27) return Wmask[k * 36 + g * 9 + (n - 18)];
  return 0.f;
}

// ---------------- Kernel W: weight fragment pack (trivial) ----------------
__global__ __launch_bounds__(256) void dcn_wpack(
    const float* __restrict__ Woff, const float* __restrict__ boff,
    const float* __restrict__ Wmask, const float* __restrict__ bmask,
    uint* __restrict__ wpk, float* __restrict__ wb) {
  const int idx = (blockIdx.x << 8) + threadIdx.x;  // grid 32 -> 8192
  {
    const int f = idx >> 8;
    const int widx = idx & 255;
    const int lane = widx >> 2, epair = widx & 3;
    const int kt = f & 3, nt = (f >> 2) & 1, g = f >> 3;
    const int k0 = kt * 32 + (lane >> 4) * 8 + epair * 2;
    const int n = nt * 16 + (lane & 15);
    wpk[idx] = pkbf(wcol(Woff, Wmask, g, k0, n), wcol(Woff, Wmask, g, k0 + 1, n));
  }
  if (blockIdx.x == 0 && threadIdx.x < 128) {
    const int g = threadIdx.x >> 5, n = threadIdx.x & 31;
    float bv;
    if (n < 18) bv = boff[g * 18 + n];
    else if (n < 27) bv = bmask[g * 9 + (n - 18)];
    else bv = 0.f;
    wb[threadIdx.x] = bv;
  }
}

// ---------------- Kernel A: dense pack + LDS-staged weights + MFMA ---------
// grid 1024, block 256 (4 waves), 64 px/block. launch_bounds (256,2):
// 256-VGPR budget so the 8 phase-0 loads + 32 B-frag reads pipeline instead
// of serializing (R9 showed 44 VGPR = zero outstanding-load headroom).
__global__ __launch_bounds__(256, 2) void dcn_lin2(
    const float* __restrict__ x, const uint* __restrict__ wpk,
    const float* __restrict__ wb, ushort* __restrict__ ws16,
    ushort* __restrict__ x16) {
  __shared__ __align__(16) uint lds[64 * 68];   // 17408 B (xtile, later rec)
  __shared__ __align__(16) uint wlds[8192];     // 32768 B (B-fragments)
  const int pbase = blockIdx.x << 6;
  const int t = threadIdx.x;

  // ---- Phase 0a: stage wpk -> LDS (dense) ----
#pragma unroll
  for (int j = 0; j < 8; ++j) {
    const int idx = (j << 8) + t;  // 2048 uint4
    *(uint4*)(wlds + (size_t)idx * 4) = *(const uint4*)(wpk + (size_t)idx * 4);
  }

  // ---- Phase 0b: dense x read -> bf16 -> LDS xtile + x16 global ----
  {
    const int px = t >> 2, part = t & 3;
    const int pix = pbase + px;
    const float* xp = x + (size_t)pix * 128 + part * 8;
    const int bb = pix >> 14, yx = pix & 16383;
#pragma unroll
    for (int g = 0; g < 4; ++g) {
      const float4 a = *(const float4*)(xp + g * 32);
      const float4 b4 = *(const float4*)(xp + g * 32 + 4);
      uint4 s;
      s.x = pkbf(a.x, a.y);
      s.y = pkbf(a.z, a.w);
      s.z = pkbf(b4.x, b4.y);
      s.w = pkbf(b4.z, b4.w);
      *(uint4*)(lds + px * 68 + g * 16 + part * 4) = s;
      *(uint4*)(x16 + ((((size_t)((g << 2) | bb) << 14) | yx) << 5) + part * 8) = s;
    }
  }
  __syncthreads();

  // ---- Phase 1: A-frags from xtile, B-frags from wlds ----
  const int wv = t >> 6;
  const int lane = t & 63;
  const int lrow = lane & 15;  // A row (px) / B col (n)
  const int lhi = lane >> 4;   // k sub-block
  const int pxrow = (wv << 4) + lrow;

  U8 afr[4];
#pragma unroll
  for (int kt = 0; kt < 4; ++kt) {
    const uint4 v = *(const uint4*)(lds + pxrow * 68 + kt * 16 + lhi * 4);
    afr[kt].u[0] = v.x; afr[kt].u[1] = v.y;
    afr[kt].u[2] = v.z; afr[kt].u[3] = v.w;
  }
  __syncthreads();  // all xtile reads done; lds free for rec reuse

  f32x4 acc[4][2];
#pragma unroll
  for (int g = 0; g < 4; ++g)
#pragma unroll
    for (int nt = 0; nt < 2; ++nt) {
      const float bv = wb[(g << 5) + (nt << 4) + lrow];
      acc[g][nt] = (f32x4){bv, bv, bv, bv};
    }

#pragma unroll
  for (int kt = 0; kt < 4; ++kt)
#pragma unroll
    for (int g = 0; g < 4; ++g)
#pragma unroll
      for (int nt = 0; nt < 2; ++nt) {
        U8 bf;
        const uint4 bv = *(const uint4*)(
            wlds + ((g << 3) + (nt << 2) + kt) * 256 + (lane << 2));
        bf.u[0] = bv.x; bf.u[1] = bv.y; bf.u[2] = bv.z; bf.u[3] = bv.w;
        acc[g][nt] =
            __builtin_amdgcn_mfma_f32_16x16x32_bf16(afr[kt].v, bf.v, acc[g][nt], 0, 0, 0);
      }

  // ---- Phase 2: record transpose into reused LDS (stride 136 ushorts) ----
  // C/D layout (m89-verified): col = lane&15 (= n), row = (lane>>4)*4 + j (= px)
  {
    ushort* rec = (ushort*)lds;
    const int px0 = (wv << 4) + (lhi << 2);
#pragma unroll
    for (int g = 0; g < 4; ++g)
#pragma unroll
      for (int nt = 0; nt < 2; ++nt)
#pragma unroll
        for (int j = 0; j < 4; ++j)
          rec[(px0 + j) * 136 + (g << 5) + (nt << 4) + lrow] = f2h(acc[g][nt][j]);
  }
  __syncthreads();

  // ---- Phase 3: coalesced copy LDS -> ws16 (16 KB) ----
  {
    const ushort* rec = (const ushort*)lds;
    ushort* dst = ws16 + (size_t)pbase * 128;
#pragma unroll
    for (int i = 0; i < 4; ++i) {
      const int idx = (i << 8) + t;  // 1024 x 16B
      const int px = idx >> 4;
      const int col = (idx & 15) << 3;
      const uint4 v = *(const uint4*)(rec + px * 136 + col);
      *(uint4*)(dst + (size_t)idx * 8) = v;
    }
  }
}

// ---------------- Kernel B: bilinear gather (R9-proven, verbatim) ----------
__global__ __launch_bounds__(256) void dcn_samp(
    const ushort* __restrict__ x16, const ushort* __restrict__ ws16,
    float* __restrict__ out) {
  const int g = blockIdx.x & 3;
  const int pg = threadIdx.x >> 2;   // 0..63: pixel within block
  const int sub = threadIdx.x & 3;   // 16B chunk within the group slice
  const int q = ((blockIdx.x >> 2) << 6) | pg;
  const int b = q >> 14;
  const int h = (q >> 7) & 127;
  const int w = q & 127;
  const ushort* xg = x16 + (((size_t)((g << 2) | b)) << 19) + (sub << 3);

  const ushort* wsrec = ws16 + (size_t)q * 128 + (g << 5);
  const uint4 r0 = *(const uint4*)(wsrec);
  const uint4 r1 = *(const uint4*)(wsrec + 8);
  const uint4 r2 = *(const uint4*)(wsrec + 16);
  const uint2 r3 = *(const uint2*)(wsrec + 24);
  const uint rr0 = r0.x, rr1 = r0.y, rr2 = r0.z, rr3 = r0.w;
  const uint rr4 = r1.x, rr5 = r1.y, rr6 = r1.z, rr7 = r1.w;
  const uint rr8 = r2.x, rr9 = r2.y, rr10 = r2.z, rr11 = r2.w;
  const uint rr12 = r3.x, rr13 = r3.y;

  float offx9[9], offy9[9], mk9[9];
  {
    const uint rra[14] = {rr0, rr1, rr2,  rr3,  rr4,  rr5,  rr6,
                          rr7, rr8, rr9, rr10, rr11, rr12, rr13};
#pragma unroll
    for (int p = 0; p < 9; ++p) {
      offx9[p] = h2f_lo(rra[p]);
      offy9[p] = h2f_hi(rra[p]);
      const int li = 18 + p;
      mk9[p] = (li & 1) ? h2f_hi(rra[li >> 1]) : h2f_lo(rra[li >> 1]);
    }
    float mx = mk9[0];
#pragma unroll
    for (int p = 1; p < 9; ++p) mx = fmaxf(mx, mk9[p]);
    float s = 0.f;
#pragma unroll
    for (int p = 0; p < 9; ++p) {
      mk9[p] = __expf(mk9[p] - mx);
      s += mk9[p];
    }
    const float sinv = 1.0f / s;
#pragma unroll
    for (int p = 0; p < 9; ++p) mk9[p] *= sinv;
  }

  float a0 = 0.f, a1 = 0.f, a2 = 0.f, a3 = 0.f;
  float a4 = 0.f, a5 = 0.f, a6 = 0.f, a7 = 0.f;

#pragma unroll
  for (int p = 0; p < 9; ++p) {
    const float mk = mk9[p];
    const float px = (float)(w + p / 3) + offx9[p];
    const float py = (float)(h + p % 3) + offy9[p];
    const float fx = floorf(px), fy = floorf(py);
    const float tx = px - fx, ty = py - fy;
    const int x0 = (int)fx - 1, y0 = (int)fy - 1;
    const int x1 = x0 + 1, y1 = y0 + 1;
    const float ax0 = ((unsigned)x0 < 128u) ? (1.f - tx) : 0.f;
    const float ax1 = ((unsigned)x1 < 128u) ? tx : 0.f;
    const float ay0 = ((unsigned)y0 < 128u) ? (mk * (1.f - ty)) : 0.f;
    const float ay1 = ((unsigned)y1 < 128u) ? (mk * ty) : 0.f;
    const float w00 = ax0 * ay0, w10 = ax1 * ay0;
    const float w01 = ax0 * ay1, w11 = ax1 * ay1;
    const int cx0 = min(max(x0, 0), 127), cy0 = min(max(y0, 0), 127);
    const int cx1 = min(max(x1, 0), 127), cy1 = min(max(y1, 0), 127);
    const int o00 = ((cy0 << 7) | cx0) << 5;
    const int o10 = ((cy0 << 7) | cx1) << 5;
    const int o01 = ((cy1 << 7) | cx0) << 5;
    const int o11 = ((cy1 << 7) | cx1) << 5;
    const uint4 d00 = *(const uint4*)(xg + o00);
    const uint4 d10 = *(const uint4*)(xg + o10);
    const uint4 d01 = *(const uint4*)(xg + o01);
    const uint4 d11 = *(const uint4*)(xg + o11);
    a0 = fmaf(w00, bflo(d00.x), fmaf(w10, bflo(d10.x),
         fmaf(w01, bflo(d01.x), fmaf(w11, bflo(d11.x), a0))));
    a1 = fmaf(w00, bfhi(d00.x), fmaf(w10, bfhi(d10.x),
         fmaf(w01, bfhi(d01.x), fmaf(w11, bfhi(d11.x), a1))));
    a2 = fmaf(w00, bflo(d00.y), fmaf(w10, bflo(d10.y),
         fmaf(w01, bflo(d01.y), fmaf(w11, bflo(d11.y), a2))));
    a3 = fmaf(w00, bfhi(d00.y), fmaf(w10, bfhi(d10.y),
         fmaf(w01, bfhi(d01.y), fmaf(w11, bfhi(d11.y), a3))));
    a4 = fmaf(w00, bflo(d00.z), fmaf(w10, bflo(d10.z),
         fmaf(w01, bflo(d01.z), fmaf(w11, bflo(d11.z), a4))));
    a5 = fmaf(w00, bfhi(d00.z), fmaf(w10, bfhi(d10.z),
         fmaf(w01, bfhi(d01.z), fmaf(w11, bfhi(d11.z), a5))));
    a6 = fmaf(w00, bflo(d00.w), fmaf(w10, bflo(d10.w),
         fmaf(w01, bflo(d01.w), fmaf(w11, bflo(d11.w), a6))));
    a7 = fmaf(w00, bfhi(d00.w), fmaf(w10, bfhi(d10.w),
         fmaf(w01, bfhi(d01.w), fmaf(w11, bfhi(d11.w), a7))));
  }

  float* op = out + (size_t)q * 128 + (g << 5) + (sub << 3);
  float4 oa, ob;
  oa.x = a0; oa.y = a1; oa.z = a2; oa.w = a3;
  ob.x = a4; ob.y = a5; ob.z = a6; ob.w = a7;
  *(float4*)op = oa;
  *(float4*)(op + 4) = ob;
}

// ---------------- Tier-2 fallback: legacy VALU lin (with softmax) ----------
__global__ __launch_bounds__(256) void dcn_lin(
    const float* __restrict__ x, const float* __restrict__ Woff,
    const float* __restrict__ boff, const float* __restrict__ Wmask,
    const float* __restrict__ bmask, float* __restrict__ ws) {
  const int jg = blockIdx.x >> 8;
  const int pix = ((blockIdx.x & 255) << 8) | threadIdx.x;
  const float* W;
  const float* bias;
  int ldw, obase;
  if (jg == 0) {
    W = Woff; bias = boff; ldw = 72; obase = 0;
  } else if (jg == 1) {
    W = Woff + 36; bias = boff + 36; ldw = 72; obase = 36;
  } else {
    W = Wmask; bias = bmask; ldw = 36; obase = 72;
  }
  float acc[36];
#pragma unroll
  for (int j = 0; j < 36; ++j) acc[j] = bias[j];
  const float* xp = x + (size_t)pix * 128;
  for (int c0 = 0; c0 < 128; c0 += 8) {
    float xr[8];
    *(float4*)(xr) = *(const float4*)(xp + c0);
    *(float4*)(xr + 4) = *(const float4*)(xp + c0 + 4);
#pragma unroll
    for (int cc = 0; cc < 8; ++cc) {
      const float xc = xr[cc];
      const float* wr = W + (size_t)(c0 + cc) * ldw;
#pragma unroll
      for (int j = 0; j < 36; ++j) acc[j] = fmaf(xc, wr[j], acc[j]);
    }
  }
  if (jg == 2) {
#pragma unroll
    for (int g = 0; g < 4; ++g) {
      float mx = acc[g * 9];
#pragma unroll
      for (int p = 1; p < 9; ++p) mx = fmaxf(mx, acc[g * 9 + p]);
      float s = 0.f;
#pragma unroll
      for (int p = 0; p < 9; ++p) {
        acc[g * 9 + p] = __expf(acc[g * 9 + p] - mx);
        s += acc[g * 9 + p];
      }
      const float sinv = 1.0f / s;
#pragma unroll
      for (int p = 0; p < 9; ++p) acc[g * 9 + p] *= sinv;
    }
  }
#pragma unroll
  for (int j = 0; j < 36; ++j) ws[(size_t)(obase + j) * NPIX + pix] = acc[j];
}

// ---------------- Tier-2 fallback: fp32 gather (R2-proven) ----------------
__global__ __launch_bounds__(256) void dcn_samp_f32(
    const float* __restrict__ x, const float* __restrict__ ws,
    float* __restrict__ out) {
  const int q = (blockIdx.x << 4) | (threadIdx.x >> 4);
  const int sub = threadIdx.x & 15;
  const int c = sub << 3;
  const int g = sub >> 2;
  const int b = q >> 14;
  const int h = (q >> 7) & 127;
  const int w = q & 127;
  const float* xb = x + ((size_t)b << 21) + c;
  const float* wsq = ws + q;
  float a0 = 0.f, a1 = 0.f, a2 = 0.f, a3 = 0.f;
  float a4 = 0.f, a5 = 0.f, a6 = 0.f, a7 = 0.f;
#pragma unroll
  for (int p = 0; p < 9; ++p) {
    const float offx = wsq[(size_t)(g * 18 + p * 2) * NPIX];
    const float offy = wsq[(size_t)(g * 18 + p * 2 + 1) * NPIX];
    const float mk = wsq[(size_t)(72 + g * 9 + p) * NPIX];
    const float px = (float)(w + p / 3) + offx;
    const float py = (float)(h + p % 3) + offy;
    const float fx = floorf(px), fy = floorf(py);
    const float tx = px - fx, ty = py - fy;
    const int x0 = (int)fx - 1, y0 = (int)fy - 1;
    const int x1 = x0 + 1, y1 = y0 + 1;
    const float ax0 = ((unsigned)x0 < 128u) ? (1.f - tx) : 0.f;
    const float ax1 = ((unsigned)x1 < 128u) ? tx : 0.f;
    const float ay0 = ((unsigned)y0 < 128u) ? (mk * (1.f - ty)) : 0.f;
    const float ay1 = ((unsigned)y1 < 128u) ? (mk * ty) : 0.f;
    const float w00 = ax0 * ay0, w10 = ax1 * ay0;
    const float w01 = ax0 * ay1, w11 = ax1 * ay1;
    const int cx0 = min(max(x0, 0), 127), cy0 = min(max(y0, 0), 127);
    const int cx1 = min(max(x1, 0), 127), cy1 = min(max(y1, 0), 127);
    const int o00 = (cy0 << 14) | (cx0 << 7), o10 = (cy0 << 14) | (cx1 << 7);
    const int o01 = (cy1 << 14) | (cx0 << 7), o11 = (cy1 << 14) | (cx1 << 7);
    const float4 v00a = *(const float4*)(xb + o00);
    const float4 v00b = *(const float4*)(xb + o00 + 4);
    const float4 v10a = *(const float4*)(xb + o10);
    const float4 v10b = *(const float4*)(xb + o10 + 4);
    const float4 v01a = *(const float4*)(xb + o01);
    const float4 v01b = *(const float4*)(xb + o01 + 4);
    const float4 v11a = *(const float4*)(xb + o11);
    const float4 v11b = *(const float4*)(xb + o11 + 4);
    a0 = fmaf(w00, v00a.x, fmaf(w10, v10a.x, fmaf(w01, v01a.x, fmaf(w11, v11a.x, a0))));
    a1 = fmaf(w00, v00a.y, fmaf(w10, v10a.y, fmaf(w01, v01a.y, fmaf(w11, v11a.y, a1))));
    a2 = fmaf(w00, v00a.z, fmaf(w10, v10a.z, fmaf(w01, v01a.z, fmaf(w11, v11a.z, a2))));
    a3 = fmaf(w00, v00a.w, fmaf(w10, v10a.w, fmaf(w01, v01a.w, fmaf(w11, v11a.w, a3))));
    a4 = fmaf(w00, v00b.x, fmaf(w10, v10b.x, fmaf(w01, v01b.x, fmaf(w11, v11b.x, a4))));
    a5 = fmaf(w00, v00b.y, fmaf(w10, v10b.y, fmaf(w01, v01b.y, fmaf(w11, v11b.y, a5))));
    a6 = fmaf(w00, v00b.z, fmaf(w10, v10b.z, fmaf(w01, v01b.z, fmaf(w11, v11b.z, a6))));
    a7 = fmaf(w00, v00b.w, fmaf(w10, v10b.w, fmaf(w01, v01b.w, fmaf(w11, v11b.w, a7))));
  }
  float4 oa, ob;
  oa.x = a0; oa.y = a1; oa.z = a2; oa.w = a3;
  ob.x = a4; ob.y = a5; ob.z = a6; ob.w = a7;
  float* op = out + (size_t)q * 128 + c;
  *(float4*)op = oa;
  *(float4*)(op + 4) = ob;
}

// ---------------- Tier-3 fallback: fully fused ----------------
__global__ __launch_bounds__(128) void dcn_fused(
    const float* __restrict__ x, const float* __restrict__ Woff,
    const float* __restrict__ boff, const float* __restrict__ Wmask,
    const float* __restrict__ bmask, float* __restrict__ out) {
  __shared__ float xs[128];
  __shared__ float res[108];
  __shared__ float msk[36];
  const int q = blockIdx.x;
  const int t = threadIdx.x;
  const int b = q >> 14, h = (q >> 7) & 127, w = q & 127;
  xs[t] = x[(size_t)q * 128 + t];
  __syncthreads();
  if (t < 108) {
    float a;
    const float* W;
    int ld;
    if (t < 72) {
      a = boff[t]; W = Woff + t; ld = 72;
    } else {
      a = bmask[t - 72]; W = Wmask + (t - 72); ld = 36;
    }
    for (int cc = 0; cc < 128; ++cc) a = fmaf(xs[cc], W[(size_t)cc * ld], a);
    res[t] = a;
  }
  __syncthreads();
  if (t < 4) {
    float mx = -1e30f;
    for (int p = 0; p < 9; ++p) mx = fmaxf(mx, res[72 + t * 9 + p]);
    float s = 0.f;
    float e[9];
    for (int p = 0; p < 9; ++p) {
      e[p] = __expf(res[72 + t * 9 + p] - mx);
      s += e[p];
    }
    for (int p = 0; p < 9; ++p) msk[t * 9 + p] = e[p] / s;
  }
  __syncthreads();
  const int g = t >> 5;
  const float* xb = x + ((size_t)b << 21) + t;
  float acc = 0.f;
#pragma unroll
  for (int p = 0; p < 9; ++p) {
    const float offx = res[g * 18 + p * 2];
    const float offy = res[g * 18 + p * 2 + 1];
    const float px = (float)(w + p / 3) + offx;
    const float py = (float)(h + p % 3) + offy;
    const float fx = floorf(px), fy = floorf(py);
    const float tx = px - fx, ty = py - fy;
    const int x0 = (int)fx - 1, y0 = (int)fy - 1;
    float sv = 0.f;
#define CORNER1(XI, YI, WT)                                       \
  if ((unsigned)(XI) < 128u && (unsigned)(YI) < 128u)             \
    sv = fmaf((WT), xb[((size_t)(YI) << 14) + ((size_t)(XI) << 7)], sv);
    CORNER1(x0, y0, (1.f - tx) * (1.f - ty))
    CORNER1(x0 + 1, y0, tx * (1.f - ty))
    CORNER1(x0, y0 + 1, (1.f - tx) * ty)
    CORNER1(x0 + 1, y0 + 1, tx * ty)
#undef CORNER1
    acc = fmaf(msk[g * 9 + p], sv, acc);
  }
  out[(size_t)q * 128 + t] = acc;
}

extern "C" void kernel_launch(void* const* d_in, const int* in_sizes, int n_in,
                              void* d_out, int out_size, void* d_ws,
                              size_t ws_size, hipStream_t stream) {
  const float* x = (const float*)d_in[0];
  const float* Woff = (const float*)d_in[1];
  const float* boff = (const float*)d_in[2];
  const float* Wmask = (const float*)d_in[3];
  const float* bmask = (const float*)d_in[4];
  float* out = (float*)d_out;
  const size_t x16_bytes = (size_t)NPIX * 128 * sizeof(ushort);   // 16 MB
  const size_t ws16_bytes = (size_t)NPIX * 128 * sizeof(ushort);  // 16 MB
  const size_t wpk_bytes = 8192 * sizeof(uint);                   // 32 KB
  const size_t need_full = x16_bytes + ws16_bytes + wpk_bytes + 512;
  const size_t need_ws = (size_t)NPIX * 108 * sizeof(float);
  if (ws_size >= need_full) {
    ushort* x16 = (ushort*)d_ws;
    ushort* ws16 = (ushort*)((char*)d_ws + x16_bytes);
    uint* wpk = (uint*)((char*)d_ws + x16_bytes + ws16_bytes);
    float* wb = (float*)((char*)d_ws + x16_bytes + ws16_bytes + wpk_bytes);
    dcn_wpack<<<32, 256, 0, stream>>>(Woff, boff, Wmask, bmask, wpk, wb);
    dcn_lin2<<<1024, 256, 0, stream>>>(x, wpk, wb, ws16, x16);
    dcn_samp<<<4096, 256, 0, stream>>>(x16, ws16, out);
  } else if (ws_size >= need_ws) {
    float* ws = (float*)d_ws;
    dcn_lin<<<768, 256, 0, stream>>>(x, Woff, boff, Wmask, bmask, ws);
    dcn_samp_f32<<<4096, 256, 0, stream>>>(x, ws, out);
  } else {
    dcn_fused<<<NPIX, 128, 0, stream>>>(x, Woff, boff, Wmask, bmask, out);
  }
}